// Round 1
// baseline (1854.296 us; speedup 1.0000x reference)
//
#include <hip/hip_runtime.h>

#define NUM_LEVELS 16
#define LEVEL_DIM 2
#define LOG2_HASHMAP 19
#define TABLE_SIZE (1u << LOG2_HASHMAP)
#define HASH_MASK (TABLE_SIZE - 1u)
#define BASE_RES 16
#define N_QUERIES (1 << 20)

// Decode the `bound` scalar: harness stores Python int as int32, but guard
// against a float32 encoding too.
__device__ __forceinline__ float decode_bound(const void* p) {
    int iv = *(const int*)p;
    float fv = __int_as_float(iv);
    float afv = fabsf(fv);
    if (afv >= 1e-8f && afv <= 1e8f) return fv;   // plausible float encoding
    return (float)iv;                              // int encoding (the expected case)
}

__global__ __launch_bounds__(256, 4)
void GridEncoderMinkowskiHierarchical_74706661147205_kernel(
    const float* __restrict__ in,    // [N,3]
    const float* __restrict__ emb,   // [L, T, 2]
    const void*  __restrict__ bound_ptr,
    float* __restrict__ out)         // [N, 32]
{
    const unsigned P1 = 2654435761u, P2 = 805459861u;
    int n = blockIdx.x * blockDim.x + threadIdx.x;
    if (n >= N_QUERIES) return;

    float bound = decode_bound(bound_ptr);

    // inputs permuted [2,0,1]: x-dim0 = in[...,2] (prime 1),
    //                          x-dim1 = in[...,0] (P1),
    //                          x-dim2 = in[...,1] (P2)
    float i0 = in[(size_t)n * 3 + 0];
    float i1 = in[(size_t)n * 3 + 1];
    float i2 = in[(size_t)n * 3 + 2];

    // u = (x / bound + 1) * 0.5 — forbid FMA contraction (must match numpy
    // bit-for-bit up to floor() decisions at high resolutions).
    float u0 = __fmul_rn(__fadd_rn(__fdiv_rn(i2, bound), 1.0f), 0.5f);
    float u1 = __fmul_rn(__fadd_rn(__fdiv_rn(i0, bound), 1.0f), 0.5f);
    float u2 = __fmul_rn(__fadd_rn(__fdiv_rn(i1, bound), 1.0f), 0.5f);

    float acc[NUM_LEVELS * 2];

    #pragma unroll 2
    for (int l = 0; l < NUM_LEVELS; ++l) {
        float res = (float)(BASE_RES << l);   // floor(16 * 2^l) exactly

        // pos = u*res - 0.5, no contraction (floor boundary sensitivity)
        float p0 = __fadd_rn(__fmul_rn(u0, res), -0.5f);
        float p1 = __fadd_rn(__fmul_rn(u1, res), -0.5f);
        float p2 = __fadd_rn(__fmul_rn(u2, res), -0.5f);
        float g0 = floorf(p0), g1 = floorf(p1), g2 = floorf(p2);
        float fr0 = __fsub_rn(p0, g0), fr1 = __fsub_rn(p1, g1), fr2 = __fsub_rn(p2, g2);
        int c0 = (int)g0, c1 = (int)g1, c2 = (int)g2;

        // hash building blocks (uint32 wraparound semantics, as jnp.uint32)
        unsigned b0  = (unsigned)c0;            // prime 1
        unsigned b0p = b0 + 1u;
        unsigned b1  = (unsigned)c1 * P1;
        unsigned b1p = b1 + P1;                 // (c1+1)*P1
        unsigned b2  = (unsigned)c2 * P2;
        unsigned b2p = b2 + P2;

        const float2* tbl = (const float2*)emb + (size_t)l * TABLE_SIZE;

        unsigned idx[8];
        // corner c = i*4 + j*2 + k  (i->dim0, j->dim1, k->dim2)
        idx[0] = (b0  ^ b1  ^ b2 ) & HASH_MASK;
        idx[1] = (b0  ^ b1  ^ b2p) & HASH_MASK;
        idx[2] = (b0  ^ b1p ^ b2 ) & HASH_MASK;
        idx[3] = (b0  ^ b1p ^ b2p) & HASH_MASK;
        idx[4] = (b0p ^ b1  ^ b2 ) & HASH_MASK;
        idx[5] = (b0p ^ b1  ^ b2p) & HASH_MASK;
        idx[6] = (b0p ^ b1p ^ b2 ) & HASH_MASK;
        idx[7] = (b0p ^ b1p ^ b2p) & HASH_MASK;

        float2 f[8];
        #pragma unroll
        for (int c = 0; c < 8; ++c) f[c] = tbl[idx[c]];   // 8 independent dwordx2 gathers

        float wx[2] = {1.0f - fr0, fr0};
        float wy[2] = {1.0f - fr1, fr1};
        float wz[2] = {1.0f - fr2, fr2};

        float a0 = 0.0f, a1 = 0.0f;
        #pragma unroll
        for (int c = 0; c < 8; ++c) {
            float w = wx[(c >> 2) & 1] * wy[(c >> 1) & 1] * wz[c & 1];
            a0 += f[c].x * w;
            a1 += f[c].y * w;
        }
        acc[2 * l]     = a0;
        acc[2 * l + 1] = a1;
    }

    // store 32 floats as 8x dwordx4 (each lane writes its own 128 B row)
    float4* o = (float4*)(out + (size_t)n * 32);
    #pragma unroll
    for (int q = 0; q < 8; ++q)
        o[q] = make_float4(acc[4 * q], acc[4 * q + 1], acc[4 * q + 2], acc[4 * q + 3]);
}

extern "C" void kernel_launch(void* const* d_in, const int* in_sizes, int n_in,
                              void* d_out, int out_size, void* d_ws, size_t ws_size,
                              hipStream_t stream) {
    const float* in   = (const float*)d_in[0];
    const float* emb  = (const float*)d_in[1];
    const void*  bptr = d_in[2];
    float* out = (float*)d_out;

    dim3 block(256);
    dim3 grid((N_QUERIES + 255) / 256);
    GridEncoderMinkowskiHierarchical_74706661147205_kernel<<<grid, block, 0, stream>>>(
        in, emb, bptr, out);
}

// Round 2
// 753.093 us; speedup vs baseline: 2.4622x; 2.4622x over previous
//
#include <hip/hip_runtime.h>

#define NUM_LEVELS 16
#define LOG2_HASHMAP 19
#define TABLE_SIZE (1u << LOG2_HASHMAP)
#define HASH_MASK (TABLE_SIZE - 1u)
#define BASE_RES 16
#define N_QUERIES (1 << 20)
#define BLK 256
#define BLOCKS_PER_LEVEL (N_QUERIES / BLK)   // 4096 blocks per level, 1 query/thread

// Decode the `bound` scalar: harness stores Python int as int32, but guard
// against a float32 encoding too.
__device__ __forceinline__ float decode_bound(const void* p) {
    int iv = *(const int*)p;
    float fv = __int_as_float(iv);
    float afv = fabsf(fv);
    if (afv >= 1e-8f && afv <= 1e8f) return fv;   // plausible float encoding
    return (float)iv;                              // int encoding (expected)
}

// Level-major gather: grid = [NUM_LEVELS * BLOCKS_PER_LEVEL], level = blockIdx /
// BLOCKS_PER_LEVEL. Blocks dispatch in ~blockIdx order, so at any instant the
// resident window (~2048 blocks) covers 1-2 levels -> each XCD L2 holds the
// active level's 4 MiB table -> gathers hit L2 instead of dragging 64 B lines
// from L3/HBM (round-1 FETCH_SIZE showed 6.4 GB = every gather missing L2).
//
// USE_WS: write level-major [L][N][2] into workspace (coalesced 8 B/lane
// contiguous), transposed to [N,32] by a second kernel. Fallback (!USE_WS):
// strided float2 writes directly into out (correct, slower write path).
template <bool USE_WS>
__global__ __launch_bounds__(BLK, 8)
void gather_kernel(const float* __restrict__ in,    // [N,3]
                   const float* __restrict__ emb,   // [L, T, 2]
                   const void*  __restrict__ bound_ptr,
                   float* __restrict__ dst)
{
    const unsigned P1 = 2654435761u, P2 = 805459861u;
    const int level = blockIdx.x / BLOCKS_PER_LEVEL;
    const int chunk = blockIdx.x % BLOCKS_PER_LEVEL;
    const int n = chunk * BLK + threadIdx.x;

    const float bound = decode_bound(bound_ptr);

    // channel permutation [2,0,1]: hash-dim0 = in[...,2], dim1 = in[...,0],
    // dim2 = in[...,1]
    float i0 = in[(size_t)n * 3 + 0];
    float i1 = in[(size_t)n * 3 + 1];
    float i2 = in[(size_t)n * 3 + 2];

    // u = (x / bound + 1) * 0.5 — forbid FMA contraction (floor() boundary
    // decisions at high res must match numpy bit-for-bit).
    float u0 = __fmul_rn(__fadd_rn(__fdiv_rn(i2, bound), 1.0f), 0.5f);
    float u1 = __fmul_rn(__fadd_rn(__fdiv_rn(i0, bound), 1.0f), 0.5f);
    float u2 = __fmul_rn(__fadd_rn(__fdiv_rn(i1, bound), 1.0f), 0.5f);

    float res = (float)(BASE_RES << level);   // floor(16 * 2^l) exact

    float p0 = __fadd_rn(__fmul_rn(u0, res), -0.5f);
    float p1 = __fadd_rn(__fmul_rn(u1, res), -0.5f);
    float p2 = __fadd_rn(__fmul_rn(u2, res), -0.5f);
    float g0 = floorf(p0), g1 = floorf(p1), g2 = floorf(p2);
    float fr0 = __fsub_rn(p0, g0), fr1 = __fsub_rn(p1, g1), fr2 = __fsub_rn(p2, g2);
    int c0 = (int)g0, c1 = (int)g1, c2 = (int)g2;

    // uint32 wraparound semantics, as jnp.uint32
    unsigned b0  = (unsigned)c0;            // prime 1
    unsigned b0p = b0 + 1u;
    unsigned b1  = (unsigned)c1 * P1;
    unsigned b1p = b1 + P1;
    unsigned b2  = (unsigned)c2 * P2;
    unsigned b2p = b2 + P2;

    const float2* tbl = (const float2*)emb + (size_t)level * TABLE_SIZE;

    unsigned idx[8];
    // corner c = i*4 + j*2 + k (i->dim0, j->dim1, k->dim2)
    idx[0] = (b0  ^ b1  ^ b2 ) & HASH_MASK;
    idx[1] = (b0  ^ b1  ^ b2p) & HASH_MASK;
    idx[2] = (b0  ^ b1p ^ b2 ) & HASH_MASK;
    idx[3] = (b0  ^ b1p ^ b2p) & HASH_MASK;
    idx[4] = (b0p ^ b1  ^ b2 ) & HASH_MASK;
    idx[5] = (b0p ^ b1  ^ b2p) & HASH_MASK;
    idx[6] = (b0p ^ b1p ^ b2 ) & HASH_MASK;
    idx[7] = (b0p ^ b1p ^ b2p) & HASH_MASK;

    float2 f[8];
    #pragma unroll
    for (int c = 0; c < 8; ++c) f[c] = tbl[idx[c]];   // 8 independent gathers

    float wx[2] = {1.0f - fr0, fr0};
    float wy[2] = {1.0f - fr1, fr1};
    float wz[2] = {1.0f - fr2, fr2};

    float a0 = 0.0f, a1 = 0.0f;
    #pragma unroll
    for (int c = 0; c < 8; ++c) {
        float w = wx[(c >> 2) & 1] * wy[(c >> 1) & 1] * wz[c & 1];
        a0 += f[c].x * w;
        a1 += f[c].y * w;
    }

    if (USE_WS) {
        // level-major [L][N][2]: wave writes 64 lanes x 8 B contiguous
        float2* o = (float2*)dst + (size_t)level * N_QUERIES + n;
        *o = make_float2(a0, a1);
    } else {
        float2* o = (float2*)(dst + (size_t)n * 32 + 2 * level);
        *o = make_float2(a0, a1);
    }
}

// Transpose [L][N][2] (ws) -> [N, 32] (out). Reads coalesced per level
// (64 lanes x 8 B contiguous), writes 128 B/thread (L2 write-combines the
// 8 float4 stores into full lines).
__global__ __launch_bounds__(BLK, 8)
void transpose_kernel(const float* __restrict__ ws, float* __restrict__ out)
{
    const int n = blockIdx.x * BLK + threadIdx.x;
    float acc[NUM_LEVELS * 2];
    #pragma unroll
    for (int l = 0; l < NUM_LEVELS; ++l) {
        float2 v = *((const float2*)ws + (size_t)l * N_QUERIES + n);
        acc[2 * l]     = v.x;
        acc[2 * l + 1] = v.y;
    }
    float4* o = (float4*)(out + (size_t)n * 32);
    #pragma unroll
    for (int q = 0; q < 8; ++q)
        o[q] = make_float4(acc[4 * q], acc[4 * q + 1], acc[4 * q + 2], acc[4 * q + 3]);
}

extern "C" void kernel_launch(void* const* d_in, const int* in_sizes, int n_in,
                              void* d_out, int out_size, void* d_ws, size_t ws_size,
                              hipStream_t stream) {
    const float* in   = (const float*)d_in[0];
    const float* emb  = (const float*)d_in[1];
    const void*  bptr = d_in[2];
    float* out = (float*)d_out;

    const size_t need = (size_t)N_QUERIES * NUM_LEVELS * 2 * sizeof(float); // 128 MiB
    dim3 block(BLK);
    dim3 ggrid(NUM_LEVELS * BLOCKS_PER_LEVEL);

    if (ws_size >= need) {
        float* ws = (float*)d_ws;
        gather_kernel<true><<<ggrid, block, 0, stream>>>(in, emb, bptr, ws);
        transpose_kernel<<<N_QUERIES / BLK, block, 0, stream>>>(ws, out);
    } else {
        gather_kernel<false><<<ggrid, block, 0, stream>>>(in, emb, bptr, out);
    }
}

// Round 3
// 735.074 us; speedup vs baseline: 2.5226x; 1.0245x over previous
//
#include <hip/hip_runtime.h>

#define NUM_LEVELS 16
#define LOG2_HASHMAP 19
#define TABLE_SIZE (1u << LOG2_HASHMAP)
#define HASH_MASK (TABLE_SIZE - 1u)
#define BASE_RES 16
#define N_QUERIES (1 << 20)
#define BLK 256
#define BLOCKS_PER_LEVEL (N_QUERIES / BLK)   // 4096 blocks per level, 1 query/thread

// Decode the `bound` scalar: harness stores Python int as int32, but guard
// against a float32 encoding too.
__device__ __forceinline__ float decode_bound(const void* p) {
    int iv = *(const int*)p;
    float fv = __int_as_float(iv);
    float afv = fabsf(fv);
    if (afv >= 1e-8f && afv <= 1e8f) return fv;   // plausible float encoding
    return (float)iv;                              // int encoding (expected)
}

// Level-major gather: grid = [NUM_LEVELS * BLOCKS_PER_LEVEL], level = blockIdx /
// BLOCKS_PER_LEVEL. Blocks dispatch in ~blockIdx order, so at any instant the
// resident window (~2048 blocks) covers ~1 level -> each XCD L2 holds the
// active level's 4 MiB table -> FETCH_SIZE is at the compulsory-miss optimum
// (measured round 2: 580 MB = 16 levels x 64Klines x 64B x 8 XCD).
//
// USE_WS: write level-major [L][N][2] into workspace (coalesced 8 B/lane
// contiguous), transposed to [N,32] by a second kernel. Fallback (!USE_WS):
// strided float2 writes directly into out (correct, slower write path).
template <bool USE_WS>
__global__ __launch_bounds__(BLK, 8)
void gather_kernel(const float* __restrict__ in,    // [N,3]
                   const float* __restrict__ emb,   // [L, T, 2]
                   const void*  __restrict__ bound_ptr,
                   float* __restrict__ dst)
{
    const unsigned P1 = 2654435761u, P2 = 805459861u;
    const int level = blockIdx.x / BLOCKS_PER_LEVEL;
    const int chunk = blockIdx.x % BLOCKS_PER_LEVEL;
    const int n = chunk * BLK + threadIdx.x;

    const float bound = decode_bound(bound_ptr);

    // channel permutation [2,0,1]: hash-dim0 = in[...,2], dim1 = in[...,0],
    // dim2 = in[...,1]
    float i0 = in[(size_t)n * 3 + 0];
    float i1 = in[(size_t)n * 3 + 1];
    float i2 = in[(size_t)n * 3 + 2];

    // u = (x / bound + 1) * 0.5 — forbid FMA contraction (floor() boundary
    // decisions at high res must match numpy bit-for-bit).
    float u0 = __fmul_rn(__fadd_rn(__fdiv_rn(i2, bound), 1.0f), 0.5f);
    float u1 = __fmul_rn(__fadd_rn(__fdiv_rn(i0, bound), 1.0f), 0.5f);
    float u2 = __fmul_rn(__fadd_rn(__fdiv_rn(i1, bound), 1.0f), 0.5f);

    float res = (float)(BASE_RES << level);   // floor(16 * 2^l) exact

    float p0 = __fadd_rn(__fmul_rn(u0, res), -0.5f);
    float p1 = __fadd_rn(__fmul_rn(u1, res), -0.5f);
    float p2 = __fadd_rn(__fmul_rn(u2, res), -0.5f);
    float g0 = floorf(p0), g1 = floorf(p1), g2 = floorf(p2);
    float fr0 = __fsub_rn(p0, g0), fr1 = __fsub_rn(p1, g1), fr2 = __fsub_rn(p2, g2);
    int c0 = (int)g0, c1 = (int)g1, c2 = (int)g2;

    // uint32 wraparound semantics, as jnp.uint32
    unsigned b0  = (unsigned)c0;            // prime 1
    unsigned b0p = b0 + 1u;
    unsigned b1  = (unsigned)c1 * P1;
    unsigned b1p = b1 + P1;
    unsigned b2  = (unsigned)c2 * P2;
    unsigned b2p = b2 + P2;

    const float2* tbl = (const float2*)emb + (size_t)level * TABLE_SIZE;

    unsigned idx[8];
    // corner c = i*4 + j*2 + k (i->dim0, j->dim1, k->dim2)
    idx[0] = (b0  ^ b1  ^ b2 ) & HASH_MASK;
    idx[1] = (b0  ^ b1  ^ b2p) & HASH_MASK;
    idx[2] = (b0  ^ b1p ^ b2 ) & HASH_MASK;
    idx[3] = (b0  ^ b1p ^ b2p) & HASH_MASK;
    idx[4] = (b0p ^ b1  ^ b2 ) & HASH_MASK;
    idx[5] = (b0p ^ b1  ^ b2p) & HASH_MASK;
    idx[6] = (b0p ^ b1p ^ b2 ) & HASH_MASK;
    idx[7] = (b0p ^ b1p ^ b2p) & HASH_MASK;

    float2 f[8];
    #pragma unroll
    for (int c = 0; c < 8; ++c) f[c] = tbl[idx[c]];   // 8 independent gathers

    float wx[2] = {1.0f - fr0, fr0};
    float wy[2] = {1.0f - fr1, fr1};
    float wz[2] = {1.0f - fr2, fr2};

    float a0 = 0.0f, a1 = 0.0f;
    #pragma unroll
    for (int c = 0; c < 8; ++c) {
        float w = wx[(c >> 2) & 1] * wy[(c >> 1) & 1] * wz[c & 1];
        a0 += f[c].x * w;
        a1 += f[c].y * w;
    }

    if (USE_WS) {
        // level-major [L][N][2]: wave writes 64 lanes x 8 B contiguous
        float2* o = (float2*)dst + (size_t)level * N_QUERIES + n;
        *o = make_float2(a0, a1);
    } else {
        float2* o = (float2*)(dst + (size_t)n * 32 + 2 * level);
        *o = make_float2(a0, a1);
    }
}

// Transpose [L][N][2] (ws) -> [N, 32] (out), one thread per OUTPUT float4.
// tid -> (n = tid>>3, q = tid&7); out float4 #tid = levels 2q, 2q+1 of query n.
// Stores: consecutive lanes write consecutive 16 B -> perfect coalescing
// (round 2's version wrote 8 float4 per thread at 128 B thread-stride: every
// wave-store hit 64 distinct lines -> 210 us instead of ~45).
// Loads: per wave-instruction, 8 runs of 8 consecutive float2 (8 full 64 B
// lines, each consumed exactly once) -> BW-bound, fine.
__global__ __launch_bounds__(BLK, 8)
void transpose_kernel(const float* __restrict__ ws, float* __restrict__ out)
{
    const int tid = blockIdx.x * BLK + threadIdx.x;   // one float4 of out
    const int n = tid >> 3;
    const int q = tid & 7;
    const float2* w = (const float2*)ws;
    float2 a = w[(size_t)(2 * q)     * N_QUERIES + n];
    float2 b = w[(size_t)(2 * q + 1) * N_QUERIES + n];
    ((float4*)out)[tid] = make_float4(a.x, a.y, b.x, b.y);
}

extern "C" void kernel_launch(void* const* d_in, const int* in_sizes, int n_in,
                              void* d_out, int out_size, void* d_ws, size_t ws_size,
                              hipStream_t stream) {
    const float* in   = (const float*)d_in[0];
    const float* emb  = (const float*)d_in[1];
    const void*  bptr = d_in[2];
    float* out = (float*)d_out;

    const size_t need = (size_t)N_QUERIES * NUM_LEVELS * 2 * sizeof(float); // 128 MiB
    dim3 block(BLK);
    dim3 ggrid(NUM_LEVELS * BLOCKS_PER_LEVEL);

    if (ws_size >= need) {
        float* ws = (float*)d_ws;
        gather_kernel<true><<<ggrid, block, 0, stream>>>(in, emb, bptr, ws);
        const int n_f4 = N_QUERIES * 8;   // one thread per out float4
        transpose_kernel<<<n_f4 / BLK, block, 0, stream>>>(ws, out);
    } else {
        gather_kernel<false><<<ggrid, block, 0, stream>>>(in, emb, bptr, out);
    }
}